// Round 1
// baseline (201.079 us; speedup 1.0000x reference)
//
#include <hip/hip_runtime.h>
#include <math.h>

#define VOX 262144  // 64^3

__device__ __forceinline__ int clampi(int v, int lo, int hi) {
    return v < lo ? lo : (v > hi ? hi : v);
}

// ---- fused prep: feat transpose (coalesced both sides) + stats zero + weight transpose ----
__global__ void k_pre(const float* __restrict__ f, float* __restrict__ ft,
                      const float* __restrict__ w, float* __restrict__ wT,
                      float* __restrict__ stats) {
    int vox = blockIdx.x * 256 + threadIdx.x;
    float v[8];
#pragma unroll
    for (int ci = 0; ci < 8; ci++) v[ci] = f[ci * VOX + vox];  // 8 coalesced reads
    float4* dst = (float4*)(ft + (size_t)vox * 8);             // coalesced 32B/thread writes
    dst[0] = make_float4(v[0], v[1], v[2], v[3]);
    dst[1] = make_float4(v[4], v[5], v[6], v[7]);

    if (blockIdx.x == 0) {
        if (threadIdx.x < 64) stats[threadIdx.x] = 0.f;  // 36 bn + 8 gn stats
    } else if (blockIdx.x == 1) {
        for (int i = threadIdx.x; i < 3888; i += 256) {  // w[c][ci][k] -> wT[k][ci][c]
            int c = i / 216, r = i % 216;
            int ci = r / 27, k = r % 27;
            wT[(k * 8 + ci) * 18 + c] = w[i];
        }
    }
}

// ---- offset conv (3x3x3, 8 -> 18 ch) + BN sum/sumsq reduction ----
// Software-pipelined: raw loads for step s+1 issued (clamped addresses, always valid)
// before consuming step s. Consume guarded by the wave-uniform bounds branch, with the
// original mh0/mh2 x-masks -> accumulation is bit-identical to the unpipelined version.
__global__ __launch_bounds__(256, 4) void k_conv_off(
        const float* __restrict__ f, const float* __restrict__ wT,
        const float* __restrict__ b, float* __restrict__ offs,
        float* __restrict__ stats) {
    int idx = blockIdx.x * 256 + threadIdx.x;
    int h = idx & 63, wy = (idx >> 6) & 63, d = idx >> 12;

    int hc0 = h > 0 ? h - 1 : 0;
    int hc2 = h < 63 ? h + 1 : 63;
    float mh0 = h > 0 ? 1.f : 0.f;
    float mh2 = h < 63 ? 1.f : 0.f;

    float acc[18];
#pragma unroll
    for (int c = 0; c < 18; c++) acc[c] = b[c];

    auto prep = [&](int s, float* V) {  // issue 24 raw loads for step s
        int kd = s / 3, kw = s % 3;
        int dc = clampi(d + kd - 1, 0, 63);
        int wc = clampi(wy + kw - 1, 0, 63);
        const float* fp = f + (dc * 64 + wc) * 64;
#pragma unroll
        for (int ci = 0; ci < 8; ci++) {
            V[3 * ci + 0] = fp[ci * VOX + hc0];
            V[3 * ci + 1] = fp[ci * VOX + h];
            V[3 * ci + 2] = fp[ci * VOX + hc2];
        }
    };

    float Va[24];
    prep(0, Va);
#pragma unroll
    for (int s = 0; s < 9; s++) {
        float Vb[24];
        if (s < 8) prep(s + 1, Vb);  // prefetch next step's loads unconditionally

        int kd = s / 3, kw = s % 3;
        int dd = d + kd - 1, ww = wy + kw - 1;
        bool ok = ((unsigned)dd < 64u) & ((unsigned)ww < 64u);  // wave-uniform
        if (ok) {
            const float* wrow = wT + s * 432;  // (kd*3+kw)*3 * 8*18
#pragma unroll
            for (int ci = 0; ci < 8; ci++) {
                float v0 = Va[3 * ci + 0] * mh0;
                float v1 = Va[3 * ci + 1];
                float v2 = Va[3 * ci + 2] * mh2;
                const float* wp = wrow + ci * 18;
#pragma unroll
                for (int c = 0; c < 18; c++) {
                    float a = acc[c];
                    a = fmaf(v0, wp[c], a);
                    a = fmaf(v1, wp[144 + c], a);
                    a = fmaf(v2, wp[288 + c], a);
                    acc[c] = a;
                }
            }
        }
#pragma unroll
        for (int j = 0; j < 24; j++) Va[j] = Vb[j];
    }

#pragma unroll
    for (int c = 0; c < 18; c++) offs[c * VOX + idx] = acc[c];

    __shared__ float ls[36];
    if (threadIdx.x < 36) ls[threadIdx.x] = 0.f;
    __syncthreads();
#pragma unroll
    for (int c = 0; c < 18; c++) {
        float s = acc[c], q = acc[c] * acc[c];
#pragma unroll
        for (int o = 32; o > 0; o >>= 1) {
            s += __shfl_xor(s, o);
            q += __shfl_xor(q, o);
        }
        if ((threadIdx.x & 63) == 0) {
            atomicAdd(&ls[c], s);
            atomicAdd(&ls[18 + c], q);
        }
    }
    __syncthreads();
    if (threadIdx.x < 36) atomicAdd(&stats[threadIdx.x], ls[threadIdx.x]);
}

// ---- main: BN affine + fast tanh + center-out cumsum + bilinear(z,y) gather + (1,1,9)
//      conv + GroupNorm stats.  Branch-free masked taps + double-buffered gather loads. ----
__global__ __launch_bounds__(256, 3) void k_main(
        const float* __restrict__ ft, const float* __restrict__ offs,
        const float* __restrict__ stats, const float* __restrict__ bn_g,
        const float* __restrict__ bn_b, const float* __restrict__ dw,
        const float* __restrict__ db, float* __restrict__ out,
        float* __restrict__ gstats) {
    int idx = blockIdx.x * 256 + threadIdx.x;
    int h = idx & 63, wy = (idx >> 6) & 63, d = idx >> 12;
    const float inv = 1.f / (float)VOX;

    float zo[9], yo[9];
#pragma unroll
    for (int c = 0; c < 18; c++) {
        float m = stats[c] * inv;
        float var = stats[18 + c] * inv - m * m;
        float rs = rsqrtf(var + 1e-5f);
        float u = bn_g[c] * ((offs[c * VOX + idx] - m) * rs) + bn_b[c];
        // fast tanh: (e^2u - 1)/(e^2u + 1); clamp keeps e^2u finite (|u|>9 -> tanh==+-1)
        u = fminf(fmaxf(u, -9.f), 9.f);
        float e2 = __expf(2.f * u);
        float t = (e2 - 1.f) * __builtin_amdgcn_rcpf(e2 + 1.f);
        if (c < 9) zo[c] = t; else yo[c - 9] = t;
    }

    // cumsum outward from center (K=9, CENTER=4)
    float za[9], ya[9];
    za[4] = zo[4]; ya[4] = yo[4];
#pragma unroll
    for (int k = 5; k < 9; k++) { za[k] = za[k - 1] + zo[k]; ya[k] = ya[k - 1] + yo[k]; }
#pragma unroll
    for (int k = 3; k >= 0; k--) { za[k] = za[k + 1] + zo[k]; ya[k] = ya[k + 1] + yo[k]; }

    float acc[16];
#pragma unroll
    for (int co = 0; co < 16; co++) acc[co] = db[co];

    // per-tap: fold the exact x-mask (0/1) into the bilinear weights; clamp xi so the
    // address is always valid. masked tap => W==0 => fmaf(0,w,acc)==acc, exact.
    auto prep = [&](int k, float4* L, float* W) {
        int xi = h + k - 4;
        float mk = (xi >= 0 && xi <= 62) ? 1.f : 0.f;
        int xc = clampi(xi, 0, 62);
        float z = (float)d + za[k];
        float y = (float)wy + ya[k];
        float fz = floorf(z), fy = floorf(y);
        int iz = (int)fz, iy = (int)fy;
        int z0 = clampi(iz, 0, 63), z1 = clampi(iz + 1, 0, 63);
        int y0 = clampi(iy, 0, 63), y1 = clampi(iy + 1, 0, 63);
        float wz0 = (float)z1 - z, wz1 = z - (float)z0;
        float wyy0 = (float)y1 - y, wyy1 = y - (float)y0;
        W[0] = wz0 * wyy0 * mk; W[1] = wz0 * wyy1 * mk;
        W[2] = wz1 * wyy0 * mk; W[3] = wz1 * wyy1 * mk;
        const float4* p00 = (const float4*)(ft + (((z0 * 64 + y0) * 64 + xc) << 3));
        const float4* p01 = (const float4*)(ft + (((z0 * 64 + y1) * 64 + xc) << 3));
        const float4* p10 = (const float4*)(ft + (((z1 * 64 + y0) * 64 + xc) << 3));
        const float4* p11 = (const float4*)(ft + (((z1 * 64 + y1) * 64 + xc) << 3));
        L[0] = p00[0]; L[1] = p00[1];
        L[2] = p01[0]; L[3] = p01[1];
        L[4] = p10[0]; L[5] = p10[1];
        L[6] = p11[0]; L[7] = p11[1];
    };

    float4 La[8]; float Wa[4];
    prep(0, La, Wa);
#pragma unroll
    for (int k = 0; k < 9; k++) {
        float4 Lb[8]; float Wb[4];
        if (k < 8) prep(k + 1, Lb, Wb);  // issue next tap's 8 float4 loads now

        float v[8];
        v[0] = Wa[0] * La[0].x + Wa[1] * La[2].x + Wa[2] * La[4].x + Wa[3] * La[6].x;
        v[1] = Wa[0] * La[0].y + Wa[1] * La[2].y + Wa[2] * La[4].y + Wa[3] * La[6].y;
        v[2] = Wa[0] * La[0].z + Wa[1] * La[2].z + Wa[2] * La[4].z + Wa[3] * La[6].z;
        v[3] = Wa[0] * La[0].w + Wa[1] * La[2].w + Wa[2] * La[4].w + Wa[3] * La[6].w;
        v[4] = Wa[0] * La[1].x + Wa[1] * La[3].x + Wa[2] * La[5].x + Wa[3] * La[7].x;
        v[5] = Wa[0] * La[1].y + Wa[1] * La[3].y + Wa[2] * La[5].y + Wa[3] * La[7].y;
        v[6] = Wa[0] * La[1].z + Wa[1] * La[3].z + Wa[2] * La[5].z + Wa[3] * La[7].z;
        v[7] = Wa[0] * La[1].w + Wa[1] * La[3].w + Wa[2] * La[5].w + Wa[3] * La[7].w;

#pragma unroll
        for (int ci = 0; ci < 8; ci++) {
#pragma unroll
            for (int co = 0; co < 16; co++)
                acc[co] = fmaf(v[ci], dw[(co * 8 + ci) * 9 + k], acc[co]);
        }
#pragma unroll
        for (int j = 0; j < 8; j++) La[j] = Lb[j];
#pragma unroll
        for (int j = 0; j < 4; j++) Wa[j] = Wb[j];
    }

#pragma unroll
    for (int co = 0; co < 16; co++) out[co * VOX + idx] = acc[co];

    // group-norm stats: 4 groups of 4 channels
    __shared__ float ls[8];
    if (threadIdx.x < 8) ls[threadIdx.x] = 0.f;
    __syncthreads();
#pragma unroll
    for (int g = 0; g < 4; g++) {
        float s = acc[4 * g] + acc[4 * g + 1] + acc[4 * g + 2] + acc[4 * g + 3];
        float q = acc[4 * g] * acc[4 * g] + acc[4 * g + 1] * acc[4 * g + 1]
                + acc[4 * g + 2] * acc[4 * g + 2] + acc[4 * g + 3] * acc[4 * g + 3];
#pragma unroll
        for (int o = 32; o > 0; o >>= 1) {
            s += __shfl_xor(s, o);
            q += __shfl_xor(q, o);
        }
        if ((threadIdx.x & 63) == 0) {
            atomicAdd(&ls[g], s);
            atomicAdd(&ls[4 + g], q);
        }
    }
    __syncthreads();
    if (threadIdx.x < 8) atomicAdd(&gstats[threadIdx.x], ls[threadIdx.x]);
}

// ---- apply GroupNorm + ReLU in place on d_out (float4) ----
__global__ void k_gn(const float* __restrict__ gstats, const float* __restrict__ gn_g,
                     const float* __restrict__ gn_b, float* __restrict__ out) {
    int i = blockIdx.x * 256 + threadIdx.x;  // over 16*VOX/4 float4s
    int c = i >> 16;                         // (i*4)/VOX
    int g = c >> 2;
    const float invn = 1.f / (4.f * (float)VOX);
    float m = gstats[g] * invn;
    float var = gstats[4 + g] * invn - m * m;
    float rs = rsqrtf(var + 1e-5f);
    float gg = gn_g[c], gb = gn_b[c];
    float4 v = ((float4*)out)[i];
    v.x = (v.x - m) * rs * gg + gb; v.x = v.x > 0.f ? v.x : 0.f;
    v.y = (v.y - m) * rs * gg + gb; v.y = v.y > 0.f ? v.y : 0.f;
    v.z = (v.z - m) * rs * gg + gb; v.z = v.z > 0.f ? v.z : 0.f;
    v.w = (v.w - m) * rs * gg + gb; v.w = v.w > 0.f ? v.w : 0.f;
    ((float4*)out)[i] = v;
}

extern "C" void kernel_launch(void* const* d_in, const int* in_sizes, int n_in,
                              void* d_out, int out_size, void* d_ws, size_t ws_size,
                              hipStream_t stream) {
    const float* f    = (const float*)d_in[0];
    const float* offw = (const float*)d_in[1];
    const float* offb = (const float*)d_in[2];
    const float* bng  = (const float*)d_in[3];
    const float* bnb  = (const float*)d_in[4];
    const float* dcnw = (const float*)d_in[5];
    const float* dcnb = (const float*)d_in[6];
    const float* gng  = (const float*)d_in[7];
    const float* gnb  = (const float*)d_in[8];
    float* out = (float*)d_out;

    float* ws    = (float*)d_ws;
    float* ft    = ws;               // 8*VOX floats (featT)
    float* offs  = ws + 8 * VOX;     // 18*VOX floats (raw offset conv)
    float* stats = offs + 18 * VOX;  // 36 bn stats + 8 gn stats
    float* gstats = stats + 36;
    // wT lives in d_out's first 3888 floats: dead until k_main overwrites out.
    float* wT = out;

    hipLaunchKernelGGL(k_pre, dim3(VOX / 256), dim3(256), 0, stream, f, ft, offw, wT, stats);
    hipLaunchKernelGGL(k_conv_off, dim3(VOX / 256), dim3(256), 0, stream,
                       f, wT, offb, offs, stats);
    hipLaunchKernelGGL(k_main, dim3(VOX / 256), dim3(256), 0, stream,
                       ft, offs, stats, bng, bnb, dcnw, dcnb, out, gstats);
    hipLaunchKernelGGL(k_gn, dim3((16 * VOX / 4) / 256), dim3(256), 0, stream,
                       gstats, gng, gnb, out);
}